// Round 1
// baseline (96.920 us; speedup 1.0000x reference)
//
#include <hip/hip_runtime.h>
#include <math.h>

#define DIM 2048
#define NB 32
#define NK 256

// ---------------- Kernel A: Bsum[b,i] = sum_j |s[b,i] - s[b,j]| ----------------
// grid (2, 4, 32): x = i-chunk (1024 i), y = j-chunk (512 j), z = batch
// block 256 threads, 4 consecutive i per thread (float4), j staged in LDS,
// inner loop reads LDS as float4 broadcast (wave-uniform address -> conflict-free).
__global__ __launch_bounds__(256) void bsum_kernel(const float* __restrict__ scores,
                                                   float* __restrict__ bsum) {
    __shared__ float4 srow[128];  // 512 floats = 2 KiB
    const int b  = blockIdx.z;
    const int j0 = blockIdx.y * 512;
    const int i0 = blockIdx.x * 1024;
    const float* row = scores + b * DIM;

    if (threadIdx.x < 128) srow[threadIdx.x] = ((const float4*)(row + j0))[threadIdx.x];
    __syncthreads();

    const float4 xi = ((const float4*)(row + i0))[threadIdx.x];
    float a0 = 0.f, a1 = 0.f, a2 = 0.f, a3 = 0.f;
    #pragma unroll 4
    for (int jj = 0; jj < 128; ++jj) {
        const float4 xj = srow[jj];
        a0 += (fabsf(xi.x - xj.x) + fabsf(xi.x - xj.y)) + (fabsf(xi.x - xj.z) + fabsf(xi.x - xj.w));
        a1 += (fabsf(xi.y - xj.x) + fabsf(xi.y - xj.y)) + (fabsf(xi.y - xj.z) + fabsf(xi.y - xj.w));
        a2 += (fabsf(xi.z - xj.x) + fabsf(xi.z - xj.y)) + (fabsf(xi.z - xj.z) + fabsf(xi.z - xj.w));
        a3 += (fabsf(xi.w - xj.x) + fabsf(xi.w - xj.y)) + (fabsf(xi.w - xj.z) + fabsf(xi.w - xj.w));
    }
    const int i = i0 + threadIdx.x * 4;
    float* dst = bsum + b * DIM + i;
    atomicAdd(dst + 0, a0);
    atomicAdd(dst + 1, a1);
    atomicAdd(dst + 2, a2);
    atomicAdd(dst + 3, a3);
}

// ---------------- Kernel B: row softmax over i for each (b,k) ----------------
// grid (256, 32): x = k, y = batch. block 256 threads, 8 i per thread.
// t[i] = s[b,i] * (2047 - 2k) - Bsum[b,i];  out[b,k,i] = softmax_i(t)
__global__ __launch_bounds__(256) void softmax_kernel(const float* __restrict__ scores,
                                                      const float* __restrict__ bsum,
                                                      float* __restrict__ out) {
    const int k   = blockIdx.x;
    const int b   = blockIdx.y;
    const int tid = threadIdx.x;
    const float scale = (float)(DIM - 1 - 2 * k);  // 2047 - 2k

    const float4* s4  = (const float4*)(scores + b * DIM);
    const float4* bs4 = (const float4*)(bsum   + b * DIM);
    const float4 sA = s4[2 * tid],  sB = s4[2 * tid + 1];
    const float4 bA = bs4[2 * tid], bB = bs4[2 * tid + 1];

    float t[8];
    t[0] = sA.x * scale - bA.x;  t[1] = sA.y * scale - bA.y;
    t[2] = sA.z * scale - bA.z;  t[3] = sA.w * scale - bA.w;
    t[4] = sB.x * scale - bB.x;  t[5] = sB.y * scale - bB.y;
    t[6] = sB.z * scale - bB.z;  t[7] = sB.w * scale - bB.w;

    // ---- block max ----
    float m = t[0];
    #pragma unroll
    for (int q = 1; q < 8; ++q) m = fmaxf(m, t[q]);
    #pragma unroll
    for (int off = 32; off > 0; off >>= 1) m = fmaxf(m, __shfl_xor(m, off, 64));

    __shared__ float redm[4];
    __shared__ float reds[4];
    const int wid = tid >> 6;
    if ((tid & 63) == 0) redm[wid] = m;
    __syncthreads();
    m = fmaxf(fmaxf(redm[0], redm[1]), fmaxf(redm[2], redm[3]));

    // ---- exp + block sum ----
    float e[8];
    float s = 0.f;
    #pragma unroll
    for (int q = 0; q < 8; ++q) { e[q] = __expf(t[q] - m); s += e[q]; }
    #pragma unroll
    for (int off = 32; off > 0; off >>= 1) s += __shfl_xor(s, off, 64);
    if ((tid & 63) == 0) reds[wid] = s;
    __syncthreads();
    s = (reds[0] + reds[1]) + (reds[2] + reds[3]);

    const float inv = 1.f / s;
    float4* o4 = (float4*)(out + ((size_t)(b * NK + k)) * DIM);
    float4 o;
    o.x = e[0] * inv; o.y = e[1] * inv; o.z = e[2] * inv; o.w = e[3] * inv;
    o4[2 * tid] = o;
    o.x = e[4] * inv; o.y = e[5] * inv; o.z = e[6] * inv; o.w = e[7] * inv;
    o4[2 * tid + 1] = o;
}

extern "C" void kernel_launch(void* const* d_in, const int* in_sizes, int n_in,
                              void* d_out, int out_size, void* d_ws, size_t ws_size,
                              hipStream_t stream) {
    const float* scores = (const float*)d_in[0];
    float* out  = (float*)d_out;
    float* bsum = (float*)d_ws;  // NB*DIM floats = 256 KiB

    hipMemsetAsync(bsum, 0, (size_t)NB * DIM * sizeof(float), stream);
    bsum_kernel<<<dim3(2, 4, NB), 256, 0, stream>>>(scores, bsum);
    softmax_kernel<<<dim3(NK, NB), 256, 0, stream>>>(scores, bsum, out);
}